// Round 12
// baseline (223.872 us; speedup 1.0000x reference)
//
#include <hip/hip_runtime.h>

typedef __bf16 bf16;
typedef bf16 bf16x2 __attribute__((ext_vector_type(2)));
typedef bf16 bf16x4 __attribute__((ext_vector_type(4)));
typedef bf16 bf16x8 __attribute__((ext_vector_type(8)));
typedef float floatx4 __attribute__((ext_vector_type(4)));
typedef float floatx16 __attribute__((ext_vector_type(16)));
typedef unsigned int uintx4 __attribute__((ext_vector_type(4)));

__device__ __forceinline__ floatx4 mfma16(bf16x8 a, bf16x8 b, floatx4 c) {
  return __builtin_amdgcn_mfma_f32_16x16x32_bf16(a, b, c, 0, 0, 0);
}
__device__ __forceinline__ floatx16 mfma32(bf16x8 a, bf16x8 b, floatx16 c) {
  return __builtin_amdgcn_mfma_f32_32x32x16_bf16(a, b, c, 0, 0, 0);
}

__device__ __forceinline__ void async_ld16(const bf16* g, bf16* lds) {
  __builtin_amdgcn_global_load_lds(
      (const __attribute__((address_space(1))) void*)g,
      (__attribute__((address_space(3))) void*)lds, 16, 0, 0);
}

// ---- fused prep (R15 version, reverted): the R17 coarse rewrite was
// neutral-to-negative (total +2.3 with flash -0.9 => non-flash +3.2).
// This is the version from the 220.9 best config.
__global__ __launch_bounds__(256) void prep(
    const float* __restrict__ x, const float* __restrict__ ctx,
    const float* __restrict__ Wq, const float* __restrict__ Wkv,
    const float* __restrict__ Wo, bf16* __restrict__ kvin,
    bf16* __restrict__ WT, bf16* __restrict__ WoT) {
  __shared__ float tile[32][33];
  int bid = blockIdx.x;
  if (bid < 6144) {
    int idx = bid * 256 + threadIdx.x;
    int row = idx >> 8;
    int c4 = (idx & 255) << 2;
    int b = row / 3072, l = row - b * 3072;
    const float* src = (l < 2048)
        ? (x + ((size_t)b * 2048 + l) * 1024 + c4)
        : (ctx + ((size_t)b * 1024 + (l - 2048)) * 1024 + c4);
    float4 v = *(const float4*)src;
    bf16x4 o = { (bf16)v.x, (bf16)v.y, (bf16)v.z, (bf16)v.w };
    *(bf16x4*)(kvin + (size_t)row * 1024 + c4) = o;
    return;
  }
  const float* W; bf16* OT; int N, t;
  if (bid < 7168)      { W = Wq;  OT = WT;                        N = 1024; t = bid - 6144; }
  else if (bid < 9216) { W = Wkv; OT = WT + (size_t)1024 * 1024;  N = 2048; t = bid - 7168; }
  else                 { W = Wo;  OT = WoT;                       N = 1024; t = bid - 9216; }
  int nb = N >> 5;
  int n0 = (t % nb) * 32, k0 = (t / nb) * 32;
  int tx = threadIdx.x & 31, ty = threadIdx.x >> 5;
  for (int i = 0; i < 4; i++) {
    int kk = ty + i * 8;
    tile[kk][tx] = W[(size_t)(k0 + kk) * N + n0 + tx];
  }
  __syncthreads();
  for (int i = 0; i < 4; i++) {
    int nn = ty + i * 8;
    OT[(size_t)(n0 + nn) * 1024 + k0 + tx] = (bf16)tile[tx][nn];
  }
}

// ---- fused QKV GEMM (R14, verified win): 256x128 tiles, BK=64, 512 thr
// (8 waves of 64x64), 16 K-steps. Swizzle: dest linear, source k-slot
// ^(row&7), read slot ((kh*4|quad)^(row&7)). 1-phase sync.
__global__ __launch_bounds__(512, 4) void gemm_qkv(
    const bf16* __restrict__ A, const bf16* __restrict__ Bt,
    const float* __restrict__ bq, const float* __restrict__ bkv,
    bf16* __restrict__ Qb, bf16* __restrict__ Kb, bf16* __restrict__ Vt) {
  int id = blockIdx.x;
  int col0, row0;
  if (id < 384) {
    col0 = 1024 + ((id & 15) << 7);
    row0 = (id >> 4) << 8;
  } else {
    int q = id - 384;
    col0 = (q & 7) << 7;
    int rb = q >> 3;
    row0 = (rb < 8 ? rb : rb + 4) << 8;
  }
  __shared__ bf16 As[256 * 64];
  __shared__ bf16 Bs[128 * 64];
  int tid = threadIdx.x;
  int wave = tid >> 6, lane = tid & 63;
  int lane15 = lane & 15, quad = lane >> 4;
  int wm = (wave & 3) * 64, wn = (wave >> 2) * 64;
  int sr = tid >> 3;                       // staging row within 64-row pass
  int ssl = ((tid & 7) ^ (sr & 7)) * 8;    // pre-swizzled source k-slot
  floatx4 acc[4][4] = {};
  for (int k0 = 0; k0 < 1024; k0 += 64) {
    for (int p = 0; p < 4; p++)
      async_ld16(A + (size_t)(row0 + p * 64 + sr) * 1024 + k0 + ssl,
                 &As[p * 4096 + tid * 8]);
    for (int p = 0; p < 2; p++)
      async_ld16(Bt + (size_t)(col0 + p * 64 + sr) * 1024 + k0 + ssl,
                 &Bs[p * 4096 + tid * 8]);
    __syncthreads();
    for (int kh = 0; kh < 2; kh++) {
      bf16x8 af[4], bfr[4];
      for (int t = 0; t < 4; t++) {
        int row = wm + t * 16 + lane15;
        af[t] = *(const bf16x8*)(
            &As[row * 64 + (((kh << 2) | quad) ^ (row & 7)) * 8]);
      }
      for (int t = 0; t < 4; t++) {
        int row = wn + t * 16 + lane15;
        bfr[t] = *(const bf16x8*)(
            &Bs[row * 64 + (((kh << 2) | quad) ^ (row & 7)) * 8]);
      }
      for (int tm = 0; tm < 4; tm++)
        for (int tn = 0; tn < 4; tn++)
          acc[tm][tn] = mfma16(af[tm], bfr[tn], acc[tm][tn]);
    }
    __syncthreads();
  }
  float bv[4];
  for (int tn = 0; tn < 4; tn++) {
    int col = col0 + wn + tn * 16 + lane15;
    bv[tn] = (col < 1024) ? bq[col] : bkv[col - 1024];
  }
  int bb = row0 / 3072;
  int l0 = row0 - bb * 3072;
  if (col0 < 1024) {           // Q (self rows guaranteed by decode)
    const float SQ = 0.18033688011f;  // 0.125 * log2(e)
    for (int tm = 0; tm < 4; tm++)
      for (int r = 0; r < 4; r++) {
        size_t grow = (size_t)bb * 2048 + l0 + wm + tm * 16 + quad * 4 + r;
        for (int tn = 0; tn < 4; tn++)
          Qb[grow * 1024 + col0 + wn + tn * 16 + lane15] =
              (bf16)((acc[tm][tn][r] + bv[tn]) * SQ);
      }
  } else if (col0 < 2048) {    // K
    for (int tm = 0; tm < 4; tm++)
      for (int r = 0; r < 4; r++) {
        size_t grow = row0 + wm + tm * 16 + quad * 4 + r;
        for (int tn = 0; tn < 4; tn++)
          Kb[grow * 1024 + (col0 - 1024) + wn + tn * 16 + lane15] =
              (bf16)(acc[tm][tn][r] + bv[tn]);
      }
  } else {                     // V, transposed
    for (int tm = 0; tm < 4; tm++) {
      int lr = l0 + wm + tm * 16 + quad * 4;
      for (int tn = 0; tn < 4; tn++) {
        int c = col0 - 2048 + wn + tn * 16 + lane15;
        bf16x4 pk = { (bf16)(acc[tm][tn][0] + bv[tn]),
                      (bf16)(acc[tm][tn][1] + bv[tn]),
                      (bf16)(acc[tm][tn][2] + bv[tn]),
                      (bf16)(acc[tm][tn][3] + bv[tn]) };
        *(bf16x4*)(Vt + ((size_t)bb * 1024 + c) * 3072 + lr) = pk;
      }
    }
  }
}

// ---- O-proj GEMM (R15, verified win): 128x64 tile, BK=64, 16 K-steps,
// same both-sides swizzle. LDS 24 KB, grid (16,32)=512 = 2/CU.
__global__ __launch_bounds__(256) void gemm_o(
    const bf16* __restrict__ A, const bf16* __restrict__ Bt,
    const float* __restrict__ bias, float* __restrict__ O) {
  int col0 = blockIdx.x * 64, row0 = blockIdx.y * 128;
  __shared__ bf16 As[128 * 64];
  __shared__ bf16 Bs[64 * 64];
  int tid = threadIdx.x;
  int wave = tid >> 6, lane = tid & 63;
  int lane15 = lane & 15, quad = lane >> 4;
  int wm = (wave & 1) * 64, wn = (wave >> 1) * 32;
  int sr = tid >> 3;                       // 0..31: staging row within pass
  int ssl = ((tid & 7) ^ (sr & 7)) * 8;    // pre-swizzled source k-slot
  floatx4 acc[4][2] = {};
  for (int k0 = 0; k0 < 1024; k0 += 64) {
    for (int p = 0; p < 4; p++)
      async_ld16(A + (size_t)(row0 + p * 32 + sr) * 1024 + k0 + ssl,
                 &As[p * 2048 + tid * 8]);
    for (int p = 0; p < 2; p++)
      async_ld16(Bt + (size_t)(col0 + p * 32 + sr) * 1024 + k0 + ssl,
                 &Bs[p * 2048 + tid * 8]);
    __syncthreads();
    for (int kh = 0; kh < 2; kh++) {
      bf16x8 af[4], bfr[2];
      for (int t = 0; t < 4; t++) {
        int row = wm + t * 16 + lane15;
        af[t] = *(const bf16x8*)(
            &As[row * 64 + (((kh << 2) | quad) ^ (row & 7)) * 8]);
      }
      for (int t = 0; t < 2; t++) {
        int row = wn + t * 16 + lane15;
        bfr[t] = *(const bf16x8*)(
            &Bs[row * 64 + (((kh << 2) | quad) ^ (row & 7)) * 8]);
      }
      for (int tm = 0; tm < 4; tm++)
        for (int tn = 0; tn < 2; tn++)
          acc[tm][tn] = mfma16(af[tm], bfr[tn], acc[tm][tn]);
    }
    __syncthreads();
  }
  float bv[2];
  for (int tn = 0; tn < 2; tn++)
    bv[tn] = bias[col0 + wn + tn * 16 + lane15];
  for (int tm = 0; tm < 4; tm++)
    for (int r = 0; r < 4; r++) {
      size_t grow = row0 + wm + tm * 16 + quad * 4 + r;
      for (int tn = 0; tn < 2; tn++)
        O[grow * 1024 + col0 + wn + tn * 16 + lane15] = acc[tm][tn][r] + bv[tn];
    }
}

// ---- flash attention (R18): R15 structure + CU-balanced qt decode.
// Diagnosis: OccupancyPercent ~32.5 vs 50 ceiling ~= mean/max work ratio
// (32.5/48) — load imbalance, not a pipe limit. Grid is capacity-exact
// (1024 = 256CU x 4); co-CU blocks are blk = c+256t (XCD round-robin,
// 256%8==0), i.e. m-groups {m, m+8, m+16, m+24} with m=blk>>5. New decode
// qt(m) = [31-i, i, 23-i, 8+i] (g=m>>3, i=m&7): bijective over 0..31,
// per-CU qt sum == 62 (total work const 130 units), longest-first kept,
// bh = blk&31 untouched (same-bh blocks stay on one XCD for K/V L2 reuse).
// Zero registers, zero loop instructions. Register ceiling intact — no
// other changes (R16 lesson: zero headroom for live state).
__global__ __launch_bounds__(256, 4) void flash_attn(
    const bf16* __restrict__ Qb, const bf16* __restrict__ Kb,
    const bf16* __restrict__ Vt, bf16* __restrict__ Ob) {
  const int LD = 72;
  __shared__ bf16 Ks[2][64 * LD];   // [grp][key][dh]
  __shared__ bf16 Vs[2][64 * LD];   // [grp][dh][key]
  int tid = threadIdx.x;
  int wave = tid >> 6, lane = tid & 63;
  int qsub = wave & 1, grp = wave >> 1;
  int l31 = lane & 31, half = lane >> 5;
  int blk = blockIdx.x;
  int m = blk >> 5;
  int g = m >> 3, i = m & 7;
  int qt = (g == 0) ? 31 - i : (g == 1) ? i : (g == 2) ? 23 - i : 8 + i;
  int bh = blk & 31;
  int h = bh & 15, b = bh >> 4;
  int q0 = qt * 64;
  int qw0 = q0 + qsub * 32;
  int qq = qw0 + l31;            // this lane's q (col of S^T)

  const bf16* qrow = Qb + ((size_t)(b * 2048 + qq)) * 1024 + h * 64 + half * 8;
  bf16x8 qf[4];
  for (int c = 0; c < 4; c++) qf[c] = *(const bf16x8*)(qrow + c * 16);

  floatx16 Oacc[2] = {};
  float l_part = 0.f;

  int nself = qt + 1;            // 64-key self tiles
  int T = nself + 16;
  int iters = (T + 1 - grp) >> 1;
  int max_iters = (T + 1) >> 1;
  const bf16* kbase = Kb + (size_t)(b * 3072) * 1024 + h * 64;
  const bf16* vbase = Vt + ((size_t)b * 1024 + h * 64) * 3072;

  int tidg = qsub * 64 + lane;
  int sr = tidg >> 1, sc = (tidg & 1) * 32;
  bf16x8 kreg[4], vreg[4];
  auto prefetch = [&](int t) {
    int keyrow = (t < nself) ? t * 64 : 2048 + (t - nself) * 64;
    const bf16* kp = kbase + (size_t)(keyrow + sr) * 1024 + sc;
    const bf16* vp = vbase + (size_t)sr * 3072 + keyrow + sc;
    for (int j = 0; j < 4; j++) {
      kreg[j] = *(const bf16x8*)(kp + j * 8);
      vreg[j] = *(const bf16x8*)(vp + j * 8);
    }
  };
  int t = grp;
  prefetch(t);

  bf16* ksg = &Ks[grp][0];
  bf16* vsg = &Vs[grp][0];
  for (int it = 0; it < max_iters; it++) {
    bool act = it < iters;
    int keyrow = 0;
    if (act) keyrow = (t < nself) ? t * 64 : 2048 + (t - nself) * 64;
    __syncthreads();
    if (act)
      for (int j = 0; j < 4; j++) {
        *(bf16x8*)(&ksg[sr * LD + sc + j * 8]) = kreg[j];
        *(bf16x8*)(&vsg[sr * LD + sc + j * 8]) = vreg[j];
      }
    __syncthreads();
    if (act && t + 2 < T) prefetch(t + 2);
    if (act) {
      bool is_self = t < nself;
      uintx4 pf[4];
      for (int kt = 0; kt < 2; kt++) {
        floatx16 st = {};
        const bf16* ka = &ksg[(kt * 32 + l31) * LD + half * 8];
        __builtin_amdgcn_s_setprio(1);
        for (int c = 0; c < 4; c++)
          st = mfma32(*(const bf16x8*)(ka + c * 16), qf[c], st);
        __builtin_amdgcn_s_setprio(0);
        bool need_mask = is_self && (keyrow + kt * 32 + 31 > qw0);
        float p[16];
        for (int r = 0; r < 16; r++) {
          float e = __builtin_amdgcn_exp2f(st[r]);
          if (need_mask) {
            int key = keyrow + kt * 32 + (r & 3) + 8 * (r >> 2) + half * 4;
            if (key > qq) e = 0.f;
          }
          p[r] = e;
          l_part += e;
        }
        unsigned pk[8];
        for (int m2 = 0; m2 < 8; m2++) {
          bf16x2 two = { (bf16)p[2 * m2], (bf16)p[2 * m2 + 1] };
          pk[m2] = __builtin_bit_cast(unsigned, two);
        }
        for (int c2 = 0; c2 < 2; c2++) {
          // swap(a,b): out0 = {a.lo_lanes, b.lo_lanes}, out1 = {a.hi, b.hi}
          auto s02 = __builtin_amdgcn_permlane32_swap(
              pk[4 * c2 + 0], pk[4 * c2 + 2], false, false);
          auto s13 = __builtin_amdgcn_permlane32_swap(
              pk[4 * c2 + 1], pk[4 * c2 + 3], false, false);
          int c = kt * 2 + c2;
          pf[c][0] = s02[0];
          pf[c][1] = s13[0];
          pf[c][2] = s02[1];
          pf[c][3] = s13[1];
        }
      }
      __builtin_amdgcn_s_setprio(1);
      for (int vt = 0; vt < 2; vt++) {
        const bf16* va = &vsg[(vt * 32 + l31) * LD + half * 8];
        for (int c = 0; c < 4; c++)
          Oacc[vt] = mfma32(__builtin_bit_cast(bf16x8, pf[c]),
                            *(const bf16x8*)(va + c * 16), Oacc[vt]);
      }
      __builtin_amdgcn_s_setprio(0);
    }
    t += 2;
  }
  float l_tot = l_part + __shfl_xor(l_part, 32, 64);
  __syncthreads();
  float* Mb = (float*)&Ks[0][0];
  float* Lg = Mb + 4096;
  if (grp == 1) {
    for (int vt = 0; vt < 2; vt++)
      for (int r = 0; r < 16; r++)
        Mb[((qsub * 2 + vt) * 16 + r) * 64 + lane] = Oacc[vt][r];
    if (half == 0) Lg[(2 + qsub) * 32 + l31] = l_tot;
  } else if (half == 0) {
    Lg[qsub * 32 + l31] = l_tot;
  }
  __syncthreads();
  if (grp == 0) {
    for (int r = 0; r < 16; r++) {
      int qr = (r & 3) + 8 * (r >> 2) + half * 4;
      float inv = 1.0f / (Lg[qsub * 32 + qr] + Lg[(2 + qsub) * 32 + qr]);
      for (int vt = 0; vt < 2; vt++) {
        float o = Oacc[vt][r] + Mb[((qsub * 2 + vt) * 16 + r) * 64 + lane];
        Ob[(size_t)(b * 2048 + qw0 + qr) * 1024 + h * 64 + vt * 32 + l31] =
            (bf16)(o * inv);
      }
    }
  }
}

extern "C" void kernel_launch(void* const* d_in, const int* in_sizes, int n_in,
                              void* d_out, int out_size, void* d_ws,
                              size_t ws_size, hipStream_t stream) {
  const float* x   = (const float*)d_in[0];
  const float* ctx = (const float*)d_in[1];
  const float* Wq  = (const float*)d_in[2];
  const float* bq  = (const float*)d_in[3];
  const float* Wkv = (const float*)d_in[4];
  const float* bkv = (const float*)d_in[5];
  const float* Wo  = (const float*)d_in[6];
  const float* bo  = (const float*)d_in[7];
  float* out = (float*)d_out;

  bf16* p = (bf16*)d_ws;
  bf16* kvin = p;   p += (size_t)6144 * 1024;      // x||context bf16
  bf16* WT   = p;   p += (size_t)3072 * 1024;      // WqT | WkvT
  bf16* WoT  = p;   p += (size_t)1024 * 1024;
  bf16* Qb   = p;   p += (size_t)4096 * 1024;
  bf16* Kb   = p;   p += (size_t)6144 * 1024;
  bf16* Vt   = p;   p += (size_t)2 * 1024 * 3072;  // V transposed [b][dh][l]
  bf16* Ob   = p;

  prep<<<10240, 256, 0, stream>>>(x, ctx, Wq, Wkv, Wo, kvin, WT, WoT);
  gemm_qkv<<<512, 512, 0, stream>>>(kvin, WT, bq, bkv, Qb, Kb, Vt);
  flash_attn<<<1024, 256, 0, stream>>>(Qb, Kb, Vt, Ob);
  gemm_o<<<dim3(16, 32), 256, 0, stream>>>(Ob, WoT, bo, out);
}

// Round 14
// 222.689 us; speedup vs baseline: 1.0053x; 1.0053x over previous
//
#include <hip/hip_runtime.h>

typedef __bf16 bf16;
typedef bf16 bf16x2 __attribute__((ext_vector_type(2)));
typedef bf16 bf16x4 __attribute__((ext_vector_type(4)));
typedef bf16 bf16x8 __attribute__((ext_vector_type(8)));
typedef float floatx4 __attribute__((ext_vector_type(4)));
typedef float floatx16 __attribute__((ext_vector_type(16)));
typedef unsigned int uintx4 __attribute__((ext_vector_type(4)));

__device__ __forceinline__ floatx4 mfma16(bf16x8 a, bf16x8 b, floatx4 c) {
  return __builtin_amdgcn_mfma_f32_16x16x32_bf16(a, b, c, 0, 0, 0);
}
__device__ __forceinline__ floatx16 mfma32(bf16x8 a, bf16x8 b, floatx16 c) {
  return __builtin_amdgcn_mfma_f32_32x32x16_bf16(a, b, c, 0, 0, 0);
}

__device__ __forceinline__ void async_ld16(const bf16* g, bf16* lds) {
  __builtin_amdgcn_global_load_lds(
      (const __attribute__((address_space(1))) void*)g,
      (__attribute__((address_space(3))) void*)lds, 16, 0, 0);
}

// ---- fused prep (R15 exact — part of the 220.9 best ensemble).
__global__ __launch_bounds__(256) void prep(
    const float* __restrict__ x, const float* __restrict__ ctx,
    const float* __restrict__ Wq, const float* __restrict__ Wkv,
    const float* __restrict__ Wo, bf16* __restrict__ kvin,
    bf16* __restrict__ WT, bf16* __restrict__ WoT) {
  __shared__ float tile[32][33];
  int bid = blockIdx.x;
  if (bid < 6144) {
    int idx = bid * 256 + threadIdx.x;
    int row = idx >> 8;
    int c4 = (idx & 255) << 2;
    int b = row / 3072, l = row - b * 3072;
    const float* src = (l < 2048)
        ? (x + ((size_t)b * 2048 + l) * 1024 + c4)
        : (ctx + ((size_t)b * 1024 + (l - 2048)) * 1024 + c4);
    float4 v = *(const float4*)src;
    bf16x4 o = { (bf16)v.x, (bf16)v.y, (bf16)v.z, (bf16)v.w };
    *(bf16x4*)(kvin + (size_t)row * 1024 + c4) = o;
    return;
  }
  const float* W; bf16* OT; int N, t;
  if (bid < 7168)      { W = Wq;  OT = WT;                        N = 1024; t = bid - 6144; }
  else if (bid < 9216) { W = Wkv; OT = WT + (size_t)1024 * 1024;  N = 2048; t = bid - 7168; }
  else                 { W = Wo;  OT = WoT;                       N = 1024; t = bid - 9216; }
  int nb = N >> 5;
  int n0 = (t % nb) * 32, k0 = (t / nb) * 32;
  int tx = threadIdx.x & 31, ty = threadIdx.x >> 5;
  for (int i = 0; i < 4; i++) {
    int kk = ty + i * 8;
    tile[kk][tx] = W[(size_t)(k0 + kk) * N + n0 + tx];
  }
  __syncthreads();
  for (int i = 0; i < 4; i++) {
    int nn = ty + i * 8;
    OT[(size_t)(n0 + nn) * 1024 + k0 + tx] = (bf16)tile[tx][nn];
  }
}

// ---- fused QKV GEMM (R19): R14 structure + XCD-chunked id remap (T1).
// FETCH was ~85 MB vs ~18 ideal: 16 consecutive ids share one 512 KB
// A-panel but round-robin 8 XCDs -> A fetched ~8x (12MB x 7-8 ~= 85).
// Remap id=(B&7)*64+(B>>3) (bijective, 512): each XCD owns a contiguous
// 64-id chunk = 4 A-row-panels x all cols; 64 blocks/XCD all co-resident
// (512=2/CU) stream K together -> A fetched ~once per chunk. Mechanism:
// 1-phase barrier drains vmcnt(0) per step, so step time includes load
// latency; L2-hit 200cyc vs HBM 900cyc.
__global__ __launch_bounds__(512, 4) void gemm_qkv(
    const bf16* __restrict__ A, const bf16* __restrict__ Bt,
    const float* __restrict__ bq, const float* __restrict__ bkv,
    bf16* __restrict__ Qb, bf16* __restrict__ Kb, bf16* __restrict__ Vt) {
  int B = blockIdx.x;
  int id = (B & 7) * 64 + (B >> 3);     // XCD-chunked (XCD = B&7 owns 64 ids)
  int col0, row0;
  if (id < 384) {
    col0 = 1024 + ((id & 15) << 7);
    row0 = (id >> 4) << 8;
  } else {
    int q = id - 384;
    col0 = (q & 7) << 7;
    int rb = q >> 3;
    row0 = (rb < 8 ? rb : rb + 4) << 8;
  }
  __shared__ bf16 As[256 * 64];
  __shared__ bf16 Bs[128 * 64];
  int tid = threadIdx.x;
  int wave = tid >> 6, lane = tid & 63;
  int lane15 = lane & 15, quad = lane >> 4;
  int wm = (wave & 3) * 64, wn = (wave >> 2) * 64;
  int sr = tid >> 3;                       // staging row within 64-row pass
  int ssl = ((tid & 7) ^ (sr & 7)) * 8;    // pre-swizzled source k-slot
  floatx4 acc[4][4] = {};
  for (int k0 = 0; k0 < 1024; k0 += 64) {
    for (int p = 0; p < 4; p++)
      async_ld16(A + (size_t)(row0 + p * 64 + sr) * 1024 + k0 + ssl,
                 &As[p * 4096 + tid * 8]);
    for (int p = 0; p < 2; p++)
      async_ld16(Bt + (size_t)(col0 + p * 64 + sr) * 1024 + k0 + ssl,
                 &Bs[p * 4096 + tid * 8]);
    __syncthreads();
    for (int kh = 0; kh < 2; kh++) {
      bf16x8 af[4], bfr[4];
      for (int t = 0; t < 4; t++) {
        int row = wm + t * 16 + lane15;
        af[t] = *(const bf16x8*)(
            &As[row * 64 + (((kh << 2) | quad) ^ (row & 7)) * 8]);
      }
      for (int t = 0; t < 4; t++) {
        int row = wn + t * 16 + lane15;
        bfr[t] = *(const bf16x8*)(
            &Bs[row * 64 + (((kh << 2) | quad) ^ (row & 7)) * 8]);
      }
      for (int tm = 0; tm < 4; tm++)
        for (int tn = 0; tn < 4; tn++)
          acc[tm][tn] = mfma16(af[tm], bfr[tn], acc[tm][tn]);
    }
    __syncthreads();
  }
  float bv[4];
  for (int tn = 0; tn < 4; tn++) {
    int col = col0 + wn + tn * 16 + lane15;
    bv[tn] = (col < 1024) ? bq[col] : bkv[col - 1024];
  }
  int bb = row0 / 3072;
  int l0 = row0 - bb * 3072;
  if (col0 < 1024) {           // Q (self rows guaranteed by decode)
    const float SQ = 0.18033688011f;  // 0.125 * log2(e)
    for (int tm = 0; tm < 4; tm++)
      for (int r = 0; r < 4; r++) {
        size_t grow = (size_t)bb * 2048 + l0 + wm + tm * 16 + quad * 4 + r;
        for (int tn = 0; tn < 4; tn++)
          Qb[grow * 1024 + col0 + wn + tn * 16 + lane15] =
              (bf16)((acc[tm][tn][r] + bv[tn]) * SQ);
      }
  } else if (col0 < 2048) {    // K
    for (int tm = 0; tm < 4; tm++)
      for (int r = 0; r < 4; r++) {
        size_t grow = row0 + wm + tm * 16 + quad * 4 + r;
        for (int tn = 0; tn < 4; tn++)
          Kb[grow * 1024 + (col0 - 1024) + wn + tn * 16 + lane15] =
              (bf16)(acc[tm][tn][r] + bv[tn]);
      }
  } else {                     // V, transposed
    for (int tm = 0; tm < 4; tm++) {
      int lr = l0 + wm + tm * 16 + quad * 4;
      for (int tn = 0; tn < 4; tn++) {
        int c = col0 - 2048 + wn + tn * 16 + lane15;
        bf16x4 pk = { (bf16)(acc[tm][tn][0] + bv[tn]),
                      (bf16)(acc[tm][tn][1] + bv[tn]),
                      (bf16)(acc[tm][tn][2] + bv[tn]),
                      (bf16)(acc[tm][tn][3] + bv[tn]) };
        *(bf16x4*)(Vt + ((size_t)bb * 1024 + c) * 3072 + lr) = pk;
      }
    }
  }
}

// ---- O-proj GEMM (R19): R15 structure + same XCD-chunked remap,
// flattened to 1D grid 512. Decode: col0=(id&15)*64, row0=(id>>4)*128.
__global__ __launch_bounds__(256) void gemm_o(
    const bf16* __restrict__ A, const bf16* __restrict__ Bt,
    const float* __restrict__ bias, float* __restrict__ O) {
  int B = blockIdx.x;
  int id = (B & 7) * 64 + (B >> 3);     // XCD-chunked
  int col0 = (id & 15) * 64, row0 = (id >> 4) * 128;
  __shared__ bf16 As[128 * 64];
  __shared__ bf16 Bs[64 * 64];
  int tid = threadIdx.x;
  int wave = tid >> 6, lane = tid & 63;
  int lane15 = lane & 15, quad = lane >> 4;
  int wm = (wave & 1) * 64, wn = (wave >> 1) * 32;
  int sr = tid >> 3;                       // 0..31: staging row within pass
  int ssl = ((tid & 7) ^ (sr & 7)) * 8;    // pre-swizzled source k-slot
  floatx4 acc[4][2] = {};
  for (int k0 = 0; k0 < 1024; k0 += 64) {
    for (int p = 0; p < 4; p++)
      async_ld16(A + (size_t)(row0 + p * 32 + sr) * 1024 + k0 + ssl,
                 &As[p * 2048 + tid * 8]);
    for (int p = 0; p < 2; p++)
      async_ld16(Bt + (size_t)(col0 + p * 32 + sr) * 1024 + k0 + ssl,
                 &Bs[p * 2048 + tid * 8]);
    __syncthreads();
    for (int kh = 0; kh < 2; kh++) {
      bf16x8 af[4], bfr[2];
      for (int t = 0; t < 4; t++) {
        int row = wm + t * 16 + lane15;
        af[t] = *(const bf16x8*)(
            &As[row * 64 + (((kh << 2) | quad) ^ (row & 7)) * 8]);
      }
      for (int t = 0; t < 2; t++) {
        int row = wn + t * 16 + lane15;
        bfr[t] = *(const bf16x8*)(
            &Bs[row * 64 + (((kh << 2) | quad) ^ (row & 7)) * 8]);
      }
      for (int tm = 0; tm < 4; tm++)
        for (int tn = 0; tn < 2; tn++)
          acc[tm][tn] = mfma16(af[tm], bfr[tn], acc[tm][tn]);
    }
    __syncthreads();
  }
  float bv[2];
  for (int tn = 0; tn < 2; tn++)
    bv[tn] = bias[col0 + wn + tn * 16 + lane15];
  for (int tm = 0; tm < 4; tm++)
    for (int r = 0; r < 4; r++) {
      size_t grow = row0 + wm + tm * 16 + quad * 4 + r;
      for (int tn = 0; tn < 2; tn++)
        O[grow * 1024 + col0 + wn + tn * 16 + lane15] = acc[tm][tn][r] + bv[tn];
    }
}

// ---- flash attention (R15 exact — the verified 60.3-61 µs floor).
// Ledger: Lacc-MFMA (R7), reg-direct K/V (R9), lp[4] split (R16), qt
// remap (R18) all regressed. Zero register headroom; decode is load-
// bearing (longest-first + bh-low-bits). Frozen.
__global__ __launch_bounds__(256, 4) void flash_attn(
    const bf16* __restrict__ Qb, const bf16* __restrict__ Kb,
    const bf16* __restrict__ Vt, bf16* __restrict__ Ob) {
  const int LD = 72;
  __shared__ bf16 Ks[2][64 * LD];   // [grp][key][dh]
  __shared__ bf16 Vs[2][64 * LD];   // [grp][dh][key]
  int tid = threadIdx.x;
  int wave = tid >> 6, lane = tid & 63;
  int qsub = wave & 1, grp = wave >> 1;
  int l31 = lane & 31, half = lane >> 5;
  int blk = blockIdx.x;
  int qt = 31 - (blk >> 5);      // longest first; bh in low bits -> same XCD
  int bh = blk & 31;
  int h = bh & 15, b = bh >> 4;
  int q0 = qt * 64;
  int qw0 = q0 + qsub * 32;
  int qq = qw0 + l31;            // this lane's q (col of S^T)

  const bf16* qrow = Qb + ((size_t)(b * 2048 + qq)) * 1024 + h * 64 + half * 8;
  bf16x8 qf[4];
  for (int c = 0; c < 4; c++) qf[c] = *(const bf16x8*)(qrow + c * 16);

  floatx16 Oacc[2] = {};
  float l_part = 0.f;

  int nself = qt + 1;            // 64-key self tiles
  int T = nself + 16;
  int iters = (T + 1 - grp) >> 1;
  int max_iters = (T + 1) >> 1;
  const bf16* kbase = Kb + (size_t)(b * 3072) * 1024 + h * 64;
  const bf16* vbase = Vt + ((size_t)b * 1024 + h * 64) * 3072;

  int tidg = qsub * 64 + lane;
  int sr = tidg >> 1, sc = (tidg & 1) * 32;
  bf16x8 kreg[4], vreg[4];
  auto prefetch = [&](int t) {
    int keyrow = (t < nself) ? t * 64 : 2048 + (t - nself) * 64;
    const bf16* kp = kbase + (size_t)(keyrow + sr) * 1024 + sc;
    const bf16* vp = vbase + (size_t)sr * 3072 + keyrow + sc;
    for (int j = 0; j < 4; j++) {
      kreg[j] = *(const bf16x8*)(kp + j * 8);
      vreg[j] = *(const bf16x8*)(vp + j * 8);
    }
  };
  int t = grp;
  prefetch(t);

  bf16* ksg = &Ks[grp][0];
  bf16* vsg = &Vs[grp][0];
  for (int it = 0; it < max_iters; it++) {
    bool act = it < iters;
    int keyrow = 0;
    if (act) keyrow = (t < nself) ? t * 64 : 2048 + (t - nself) * 64;
    __syncthreads();
    if (act)
      for (int j = 0; j < 4; j++) {
        *(bf16x8*)(&ksg[sr * LD + sc + j * 8]) = kreg[j];
        *(bf16x8*)(&vsg[sr * LD + sc + j * 8]) = vreg[j];
      }
    __syncthreads();
    if (act && t + 2 < T) prefetch(t + 2);
    if (act) {
      bool is_self = t < nself;
      uintx4 pf[4];
      for (int kt = 0; kt < 2; kt++) {
        floatx16 st = {};
        const bf16* ka = &ksg[(kt * 32 + l31) * LD + half * 8];
        __builtin_amdgcn_s_setprio(1);
        for (int c = 0; c < 4; c++)
          st = mfma32(*(const bf16x8*)(ka + c * 16), qf[c], st);
        __builtin_amdgcn_s_setprio(0);
        bool need_mask = is_self && (keyrow + kt * 32 + 31 > qw0);
        float p[16];
        for (int r = 0; r < 16; r++) {
          float e = __builtin_amdgcn_exp2f(st[r]);
          if (need_mask) {
            int key = keyrow + kt * 32 + (r & 3) + 8 * (r >> 2) + half * 4;
            if (key > qq) e = 0.f;
          }
          p[r] = e;
          l_part += e;
        }
        unsigned pk[8];
        for (int m2 = 0; m2 < 8; m2++) {
          bf16x2 two = { (bf16)p[2 * m2], (bf16)p[2 * m2 + 1] };
          pk[m2] = __builtin_bit_cast(unsigned, two);
        }
        for (int c2 = 0; c2 < 2; c2++) {
          // swap(a,b): out0 = {a.lo_lanes, b.lo_lanes}, out1 = {a.hi, b.hi}
          auto s02 = __builtin_amdgcn_permlane32_swap(
              pk[4 * c2 + 0], pk[4 * c2 + 2], false, false);
          auto s13 = __builtin_amdgcn_permlane32_swap(
              pk[4 * c2 + 1], pk[4 * c2 + 3], false, false);
          int c = kt * 2 + c2;
          pf[c][0] = s02[0];
          pf[c][1] = s13[0];
          pf[c][2] = s02[1];
          pf[c][3] = s13[1];
        }
      }
      __builtin_amdgcn_s_setprio(1);
      for (int vt = 0; vt < 2; vt++) {
        const bf16* va = &vsg[(vt * 32 + l31) * LD + half * 8];
        for (int c = 0; c < 4; c++)
          Oacc[vt] = mfma32(__builtin_bit_cast(bf16x8, pf[c]),
                            *(const bf16x8*)(va + c * 16), Oacc[vt]);
      }
      __builtin_amdgcn_s_setprio(0);
    }
    t += 2;
  }
  float l_tot = l_part + __shfl_xor(l_part, 32, 64);
  __syncthreads();
  float* Mb = (float*)&Ks[0][0];
  float* Lg = Mb + 4096;
  if (grp == 1) {
    for (int vt = 0; vt < 2; vt++)
      for (int r = 0; r < 16; r++)
        Mb[((qsub * 2 + vt) * 16 + r) * 64 + lane] = Oacc[vt][r];
    if (half == 0) Lg[(2 + qsub) * 32 + l31] = l_tot;
  } else if (half == 0) {
    Lg[qsub * 32 + l31] = l_tot;
  }
  __syncthreads();
  if (grp == 0) {
    for (int r = 0; r < 16; r++) {
      int qr = (r & 3) + 8 * (r >> 2) + half * 4;
      float inv = 1.0f / (Lg[qsub * 32 + qr] + Lg[(2 + qsub) * 32 + qr]);
      for (int vt = 0; vt < 2; vt++) {
        float o = Oacc[vt][r] + Mb[((qsub * 2 + vt) * 16 + r) * 64 + lane];
        Ob[(size_t)(b * 2048 + qw0 + qr) * 1024 + h * 64 + vt * 32 + l31] =
            (bf16)(o * inv);
      }
    }
  }
}

extern "C" void kernel_launch(void* const* d_in, const int* in_sizes, int n_in,
                              void* d_out, int out_size, void* d_ws,
                              size_t ws_size, hipStream_t stream) {
  const float* x   = (const float*)d_in[0];
  const float* ctx = (const float*)d_in[1];
  const float* Wq  = (const float*)d_in[2];
  const float* bq  = (const float*)d_in[3];
  const float* Wkv = (const float*)d_in[4];
  const float* bkv = (const float*)d_in[5];
  const float* Wo  = (const float*)d_in[6];
  const float* bo  = (const float*)d_in[7];
  float* out = (float*)d_out;

  bf16* p = (bf16*)d_ws;
  bf16* kvin = p;   p += (size_t)6144 * 1024;      // x||context bf16
  bf16* WT   = p;   p += (size_t)3072 * 1024;      // WqT | WkvT
  bf16* WoT  = p;   p += (size_t)1024 * 1024;
  bf16* Qb   = p;   p += (size_t)4096 * 1024;
  bf16* Kb   = p;   p += (size_t)6144 * 1024;
  bf16* Vt   = p;   p += (size_t)2 * 1024 * 3072;  // V transposed [b][dh][l]
  bf16* Ob   = p;

  prep<<<10240, 256, 0, stream>>>(x, ctx, Wq, Wkv, Wo, kvin, WT, WoT);
  gemm_qkv<<<512, 512, 0, stream>>>(kvin, WT, bq, bkv, Qb, Kb, Vt);
  flash_attn<<<1024, 256, 0, stream>>>(Qb, Kb, Vt, Ob);
  gemm_o<<<512, 256, 0, stream>>>(Ob, WoT, bo, out);
}

// Round 15
// 221.279 us; speedup vs baseline: 1.0117x; 1.0064x over previous
//
#include <hip/hip_runtime.h>

typedef __bf16 bf16;
typedef bf16 bf16x2 __attribute__((ext_vector_type(2)));
typedef bf16 bf16x4 __attribute__((ext_vector_type(4)));
typedef bf16 bf16x8 __attribute__((ext_vector_type(8)));
typedef float floatx4 __attribute__((ext_vector_type(4)));
typedef float floatx16 __attribute__((ext_vector_type(16)));
typedef unsigned int uintx4 __attribute__((ext_vector_type(4)));

__device__ __forceinline__ floatx4 mfma16(bf16x8 a, bf16x8 b, floatx4 c) {
  return __builtin_amdgcn_mfma_f32_16x16x32_bf16(a, b, c, 0, 0, 0);
}
__device__ __forceinline__ floatx16 mfma32(bf16x8 a, bf16x8 b, floatx16 c) {
  return __builtin_amdgcn_mfma_f32_32x32x16_bf16(a, b, c, 0, 0, 0);
}

__device__ __forceinline__ void async_ld16(const bf16* g, bf16* lds) {
  __builtin_amdgcn_global_load_lds(
      (const __attribute__((address_space(1))) void*)g,
      (__attribute__((address_space(3))) void*)lds, 16, 0, 0);
}

// ---- fused prep: convert x||ctx -> kvin bf16, + transpose Wq/Wkv/Wo -> bf16
__global__ __launch_bounds__(256) void prep(
    const float* __restrict__ x, const float* __restrict__ ctx,
    const float* __restrict__ Wq, const float* __restrict__ Wkv,
    const float* __restrict__ Wo, bf16* __restrict__ kvin,
    bf16* __restrict__ WT, bf16* __restrict__ WoT) {
  __shared__ float tile[32][33];
  int bid = blockIdx.x;
  if (bid < 6144) {
    int idx = bid * 256 + threadIdx.x;
    int row = idx >> 8;
    int c4 = (idx & 255) << 2;
    int b = row / 3072, l = row - b * 3072;
    const float* src = (l < 2048)
        ? (x + ((size_t)b * 2048 + l) * 1024 + c4)
        : (ctx + ((size_t)b * 1024 + (l - 2048)) * 1024 + c4);
    float4 v = *(const float4*)src;
    bf16x4 o = { (bf16)v.x, (bf16)v.y, (bf16)v.z, (bf16)v.w };
    *(bf16x4*)(kvin + (size_t)row * 1024 + c4) = o;
    return;
  }
  const float* W; bf16* OT; int N, t;
  if (bid < 7168)      { W = Wq;  OT = WT;                        N = 1024; t = bid - 6144; }
  else if (bid < 9216) { W = Wkv; OT = WT + (size_t)1024 * 1024;  N = 2048; t = bid - 7168; }
  else                 { W = Wo;  OT = WoT;                       N = 1024; t = bid - 9216; }
  int nb = N >> 5;
  int n0 = (t % nb) * 32, k0 = (t / nb) * 32;
  int tx = threadIdx.x & 31, ty = threadIdx.x >> 5;
  for (int i = 0; i < 4; i++) {
    int kk = ty + i * 8;
    tile[kk][tx] = W[(size_t)(k0 + kk) * N + n0 + tx];
  }
  __syncthreads();
  for (int i = 0; i < 4; i++) {
    int nn = ty + i * 8;
    OT[(size_t)(n0 + nn) * 1024 + k0 + tx] = (bf16)tile[tx][nn];
  }
}

// ---- fused QKV GEMM (R14, verified win): 256x128 tiles, BK=64, 512 thr
// (8 waves of 64x64), 16 K-steps. Swizzle: dest linear, source k-slot
// ^(row&7), read slot ((kh*4|quad)^(row&7)). 1-phase sync. Original id
// decode (both XCD remap variants R18/R19 were neutral-to-negative).
__global__ __launch_bounds__(512, 4) void gemm_qkv(
    const bf16* __restrict__ A, const bf16* __restrict__ Bt,
    const float* __restrict__ bq, const float* __restrict__ bkv,
    bf16* __restrict__ Qb, bf16* __restrict__ Kb, bf16* __restrict__ Vt) {
  int id = blockIdx.x;
  int col0, row0;
  if (id < 384) {
    col0 = 1024 + ((id & 15) << 7);
    row0 = (id >> 4) << 8;
  } else {
    int q = id - 384;
    col0 = (q & 7) << 7;
    int rb = q >> 3;
    row0 = (rb < 8 ? rb : rb + 4) << 8;
  }
  __shared__ bf16 As[256 * 64];
  __shared__ bf16 Bs[128 * 64];
  int tid = threadIdx.x;
  int wave = tid >> 6, lane = tid & 63;
  int lane15 = lane & 15, quad = lane >> 4;
  int wm = (wave & 3) * 64, wn = (wave >> 2) * 64;
  int sr = tid >> 3;                       // staging row within 64-row pass
  int ssl = ((tid & 7) ^ (sr & 7)) * 8;    // pre-swizzled source k-slot
  floatx4 acc[4][4] = {};
  for (int k0 = 0; k0 < 1024; k0 += 64) {
    for (int p = 0; p < 4; p++)
      async_ld16(A + (size_t)(row0 + p * 64 + sr) * 1024 + k0 + ssl,
                 &As[p * 4096 + tid * 8]);
    for (int p = 0; p < 2; p++)
      async_ld16(Bt + (size_t)(col0 + p * 64 + sr) * 1024 + k0 + ssl,
                 &Bs[p * 4096 + tid * 8]);
    __syncthreads();
    for (int kh = 0; kh < 2; kh++) {
      bf16x8 af[4], bfr[4];
      for (int t = 0; t < 4; t++) {
        int row = wm + t * 16 + lane15;
        af[t] = *(const bf16x8*)(
            &As[row * 64 + (((kh << 2) | quad) ^ (row & 7)) * 8]);
      }
      for (int t = 0; t < 4; t++) {
        int row = wn + t * 16 + lane15;
        bfr[t] = *(const bf16x8*)(
            &Bs[row * 64 + (((kh << 2) | quad) ^ (row & 7)) * 8]);
      }
      for (int tm = 0; tm < 4; tm++)
        for (int tn = 0; tn < 4; tn++)
          acc[tm][tn] = mfma16(af[tm], bfr[tn], acc[tm][tn]);
    }
    __syncthreads();
  }
  float bv[4];
  for (int tn = 0; tn < 4; tn++) {
    int col = col0 + wn + tn * 16 + lane15;
    bv[tn] = (col < 1024) ? bq[col] : bkv[col - 1024];
  }
  int bb = row0 / 3072;
  int l0 = row0 - bb * 3072;
  if (col0 < 1024) {           // Q (self rows guaranteed by decode)
    const float SQ = 0.18033688011f;  // 0.125 * log2(e)
    for (int tm = 0; tm < 4; tm++)
      for (int r = 0; r < 4; r++) {
        size_t grow = (size_t)bb * 2048 + l0 + wm + tm * 16 + quad * 4 + r;
        for (int tn = 0; tn < 4; tn++)
          Qb[grow * 1024 + col0 + wn + tn * 16 + lane15] =
              (bf16)((acc[tm][tn][r] + bv[tn]) * SQ);
      }
  } else if (col0 < 2048) {    // K
    for (int tm = 0; tm < 4; tm++)
      for (int r = 0; r < 4; r++) {
        size_t grow = row0 + wm + tm * 16 + quad * 4 + r;
        for (int tn = 0; tn < 4; tn++)
          Kb[grow * 1024 + (col0 - 1024) + wn + tn * 16 + lane15] =
              (bf16)(acc[tm][tn][r] + bv[tn]);
      }
  } else {                     // V, transposed
    for (int tm = 0; tm < 4; tm++) {
      int lr = l0 + wm + tm * 16 + quad * 4;
      for (int tn = 0; tn < 4; tn++) {
        int c = col0 - 2048 + wn + tn * 16 + lane15;
        bf16x4 pk = { (bf16)(acc[tm][tn][0] + bv[tn]),
                      (bf16)(acc[tm][tn][1] + bv[tn]),
                      (bf16)(acc[tm][tn][2] + bv[tn]),
                      (bf16)(acc[tm][tn][3] + bv[tn]) };
        *(bf16x4*)(Vt + ((size_t)bb * 1024 + c) * 3072 + lr) = pk;
      }
    }
  }
}

// ---- O-proj GEMM (R15, verified win): 128x64 tile, BK=64, 16 K-steps,
// same both-sides swizzle. LDS 24 KB, grid (16,32)=512 = 2/CU.
__global__ __launch_bounds__(256) void gemm_o(
    const bf16* __restrict__ A, const bf16* __restrict__ Bt,
    const float* __restrict__ bias, float* __restrict__ O) {
  int col0 = blockIdx.x * 64, row0 = blockIdx.y * 128;
  __shared__ bf16 As[128 * 64];
  __shared__ bf16 Bs[64 * 64];
  int tid = threadIdx.x;
  int wave = tid >> 6, lane = tid & 63;
  int lane15 = lane & 15, quad = lane >> 4;
  int wm = (wave & 1) * 64, wn = (wave >> 1) * 32;
  int sr = tid >> 3;                       // 0..31: staging row within pass
  int ssl = ((tid & 7) ^ (sr & 7)) * 8;    // pre-swizzled source k-slot
  floatx4 acc[4][2] = {};
  for (int k0 = 0; k0 < 1024; k0 += 64) {
    for (int p = 0; p < 4; p++)
      async_ld16(A + (size_t)(row0 + p * 32 + sr) * 1024 + k0 + ssl,
                 &As[p * 2048 + tid * 8]);
    for (int p = 0; p < 2; p++)
      async_ld16(Bt + (size_t)(col0 + p * 32 + sr) * 1024 + k0 + ssl,
                 &Bs[p * 2048 + tid * 8]);
    __syncthreads();
    for (int kh = 0; kh < 2; kh++) {
      bf16x8 af[4], bfr[2];
      for (int t = 0; t < 4; t++) {
        int row = wm + t * 16 + lane15;
        af[t] = *(const bf16x8*)(
            &As[row * 64 + (((kh << 2) | quad) ^ (row & 7)) * 8]);
      }
      for (int t = 0; t < 2; t++) {
        int row = wn + t * 16 + lane15;
        bfr[t] = *(const bf16x8*)(
            &Bs[row * 64 + (((kh << 2) | quad) ^ (row & 7)) * 8]);
      }
      for (int tm = 0; tm < 4; tm++)
        for (int tn = 0; tn < 2; tn++)
          acc[tm][tn] = mfma16(af[tm], bfr[tn], acc[tm][tn]);
    }
    __syncthreads();
  }
  float bv[2];
  for (int tn = 0; tn < 2; tn++)
    bv[tn] = bias[col0 + wn + tn * 16 + lane15];
  for (int tm = 0; tm < 4; tm++)
    for (int r = 0; r < 4; r++) {
      size_t grow = row0 + wm + tm * 16 + quad * 4 + r;
      for (int tn = 0; tn < 2; tn++)
        O[grow * 1024 + col0 + wn + tn * 16 + lane15] = acc[tm][tn][r] + bv[tn];
    }
}

// ---- flash attention (R15 exact — the verified 60.3-61 µs floor).
// Ledger: Lacc-MFMA (R7), reg-direct K/V (R9), lp[4] split (R16), qt
// remap (R18) all regressed. Zero register headroom; decode is load-
// bearing (longest-first + bh-low-bits). Frozen.
__global__ __launch_bounds__(256, 4) void flash_attn(
    const bf16* __restrict__ Qb, const bf16* __restrict__ Kb,
    const bf16* __restrict__ Vt, bf16* __restrict__ Ob) {
  const int LD = 72;
  __shared__ bf16 Ks[2][64 * LD];   // [grp][key][dh]
  __shared__ bf16 Vs[2][64 * LD];   // [grp][dh][key]
  int tid = threadIdx.x;
  int wave = tid >> 6, lane = tid & 63;
  int qsub = wave & 1, grp = wave >> 1;
  int l31 = lane & 31, half = lane >> 5;
  int blk = blockIdx.x;
  int qt = 31 - (blk >> 5);      // longest first; bh in low bits -> same XCD
  int bh = blk & 31;
  int h = bh & 15, b = bh >> 4;
  int q0 = qt * 64;
  int qw0 = q0 + qsub * 32;
  int qq = qw0 + l31;            // this lane's q (col of S^T)

  const bf16* qrow = Qb + ((size_t)(b * 2048 + qq)) * 1024 + h * 64 + half * 8;
  bf16x8 qf[4];
  for (int c = 0; c < 4; c++) qf[c] = *(const bf16x8*)(qrow + c * 16);

  floatx16 Oacc[2] = {};
  float l_part = 0.f;

  int nself = qt + 1;            // 64-key self tiles
  int T = nself + 16;
  int iters = (T + 1 - grp) >> 1;
  int max_iters = (T + 1) >> 1;
  const bf16* kbase = Kb + (size_t)(b * 3072) * 1024 + h * 64;
  const bf16* vbase = Vt + ((size_t)b * 1024 + h * 64) * 3072;

  int tidg = qsub * 64 + lane;
  int sr = tidg >> 1, sc = (tidg & 1) * 32;
  bf16x8 kreg[4], vreg[4];
  auto prefetch = [&](int t) {
    int keyrow = (t < nself) ? t * 64 : 2048 + (t - nself) * 64;
    const bf16* kp = kbase + (size_t)(keyrow + sr) * 1024 + sc;
    const bf16* vp = vbase + (size_t)sr * 3072 + keyrow + sc;
    for (int j = 0; j < 4; j++) {
      kreg[j] = *(const bf16x8*)(kp + j * 8);
      vreg[j] = *(const bf16x8*)(vp + j * 8);
    }
  };
  int t = grp;
  prefetch(t);

  bf16* ksg = &Ks[grp][0];
  bf16* vsg = &Vs[grp][0];
  for (int it = 0; it < max_iters; it++) {
    bool act = it < iters;
    int keyrow = 0;
    if (act) keyrow = (t < nself) ? t * 64 : 2048 + (t - nself) * 64;
    __syncthreads();
    if (act)
      for (int j = 0; j < 4; j++) {
        *(bf16x8*)(&ksg[sr * LD + sc + j * 8]) = kreg[j];
        *(bf16x8*)(&vsg[sr * LD + sc + j * 8]) = vreg[j];
      }
    __syncthreads();
    if (act && t + 2 < T) prefetch(t + 2);
    if (act) {
      bool is_self = t < nself;
      uintx4 pf[4];
      for (int kt = 0; kt < 2; kt++) {
        floatx16 st = {};
        const bf16* ka = &ksg[(kt * 32 + l31) * LD + half * 8];
        __builtin_amdgcn_s_setprio(1);
        for (int c = 0; c < 4; c++)
          st = mfma32(*(const bf16x8*)(ka + c * 16), qf[c], st);
        __builtin_amdgcn_s_setprio(0);
        bool need_mask = is_self && (keyrow + kt * 32 + 31 > qw0);
        float p[16];
        for (int r = 0; r < 16; r++) {
          float e = __builtin_amdgcn_exp2f(st[r]);
          if (need_mask) {
            int key = keyrow + kt * 32 + (r & 3) + 8 * (r >> 2) + half * 4;
            if (key > qq) e = 0.f;
          }
          p[r] = e;
          l_part += e;
        }
        unsigned pk[8];
        for (int m2 = 0; m2 < 8; m2++) {
          bf16x2 two = { (bf16)p[2 * m2], (bf16)p[2 * m2 + 1] };
          pk[m2] = __builtin_bit_cast(unsigned, two);
        }
        for (int c2 = 0; c2 < 2; c2++) {
          // swap(a,b): out0 = {a.lo_lanes, b.lo_lanes}, out1 = {a.hi, b.hi}
          auto s02 = __builtin_amdgcn_permlane32_swap(
              pk[4 * c2 + 0], pk[4 * c2 + 2], false, false);
          auto s13 = __builtin_amdgcn_permlane32_swap(
              pk[4 * c2 + 1], pk[4 * c2 + 3], false, false);
          int c = kt * 2 + c2;
          pf[c][0] = s02[0];
          pf[c][1] = s13[0];
          pf[c][2] = s02[1];
          pf[c][3] = s13[1];
        }
      }
      __builtin_amdgcn_s_setprio(1);
      for (int vt = 0; vt < 2; vt++) {
        const bf16* va = &vsg[(vt * 32 + l31) * LD + half * 8];
        for (int c = 0; c < 4; c++)
          Oacc[vt] = mfma32(__builtin_bit_cast(bf16x8, pf[c]),
                            *(const bf16x8*)(va + c * 16), Oacc[vt]);
      }
      __builtin_amdgcn_s_setprio(0);
    }
    t += 2;
  }
  float l_tot = l_part + __shfl_xor(l_part, 32, 64);
  __syncthreads();
  float* Mb = (float*)&Ks[0][0];
  float* Lg = Mb + 4096;
  if (grp == 1) {
    for (int vt = 0; vt < 2; vt++)
      for (int r = 0; r < 16; r++)
        Mb[((qsub * 2 + vt) * 16 + r) * 64 + lane] = Oacc[vt][r];
    if (half == 0) Lg[(2 + qsub) * 32 + l31] = l_tot;
  } else if (half == 0) {
    Lg[qsub * 32 + l31] = l_tot;
  }
  __syncthreads();
  if (grp == 0) {
    for (int r = 0; r < 16; r++) {
      int qr = (r & 3) + 8 * (r >> 2) + half * 4;
      float inv = 1.0f / (Lg[qsub * 32 + qr] + Lg[(2 + qsub) * 32 + qr]);
      for (int vt = 0; vt < 2; vt++) {
        float o = Oacc[vt][r] + Mb[((qsub * 2 + vt) * 16 + r) * 64 + lane];
        Ob[(size_t)(b * 2048 + qw0 + qr) * 1024 + h * 64 + vt * 32 + l31] =
            (bf16)(o * inv);
      }
    }
  }
}

extern "C" void kernel_launch(void* const* d_in, const int* in_sizes, int n_in,
                              void* d_out, int out_size, void* d_ws,
                              size_t ws_size, hipStream_t stream) {
  const float* x   = (const float*)d_in[0];
  const float* ctx = (const float*)d_in[1];
  const float* Wq  = (const float*)d_in[2];
  const float* bq  = (const float*)d_in[3];
  const float* Wkv = (const float*)d_in[4];
  const float* bkv = (const float*)d_in[5];
  const float* Wo  = (const float*)d_in[6];
  const float* bo  = (const float*)d_in[7];
  float* out = (float*)d_out;

  bf16* p = (bf16*)d_ws;
  bf16* kvin = p;   p += (size_t)6144 * 1024;      // x||context bf16
  bf16* WT   = p;   p += (size_t)3072 * 1024;      // WqT | WkvT
  bf16* WoT  = p;   p += (size_t)1024 * 1024;
  bf16* Qb   = p;   p += (size_t)4096 * 1024;
  bf16* Kb   = p;   p += (size_t)6144 * 1024;
  bf16* Vt   = p;   p += (size_t)2 * 1024 * 3072;  // V transposed [b][dh][l]
  bf16* Ob   = p;

  prep<<<10240, 256, 0, stream>>>(x, ctx, Wq, Wkv, Wo, kvin, WT, WoT);
  gemm_qkv<<<512, 512, 0, stream>>>(kvin, WT, bq, bkv, Qb, Kb, Vt);
  flash_attn<<<1024, 256, 0, stream>>>(Qb, Kb, Vt, Ob);
  gemm_o<<<dim3(16, 32), 256, 0, stream>>>(Ob, WoT, bo, out);
}

// Round 16
// 218.859 us; speedup vs baseline: 1.0229x; 1.0111x over previous
//
#include <hip/hip_runtime.h>

typedef __bf16 bf16;
typedef bf16 bf16x2 __attribute__((ext_vector_type(2)));
typedef bf16 bf16x4 __attribute__((ext_vector_type(4)));
typedef bf16 bf16x8 __attribute__((ext_vector_type(8)));
typedef float floatx4 __attribute__((ext_vector_type(4)));
typedef float floatx16 __attribute__((ext_vector_type(16)));
typedef unsigned int uintx4 __attribute__((ext_vector_type(4)));

__device__ __forceinline__ floatx4 mfma16(bf16x8 a, bf16x8 b, floatx4 c) {
  return __builtin_amdgcn_mfma_f32_16x16x32_bf16(a, b, c, 0, 0, 0);
}
__device__ __forceinline__ floatx16 mfma32(bf16x8 a, bf16x8 b, floatx16 c) {
  return __builtin_amdgcn_mfma_f32_32x32x16_bf16(a, b, c, 0, 0, 0);
}

__device__ __forceinline__ void async_ld16(const bf16* g, bf16* lds) {
  __builtin_amdgcn_global_load_lds(
      (const __attribute__((address_space(1))) void*)g,
      (__attribute__((address_space(3))) void*)lds, 16, 0, 0);
}

// ---- fused prep (R15 exact — part of the verified-best ensemble).
__global__ __launch_bounds__(256) void prep(
    const float* __restrict__ x, const float* __restrict__ ctx,
    const float* __restrict__ Wq, const float* __restrict__ Wkv,
    const float* __restrict__ Wo, bf16* __restrict__ kvin,
    bf16* __restrict__ WT, bf16* __restrict__ WoT) {
  __shared__ float tile[32][33];
  int bid = blockIdx.x;
  if (bid < 6144) {
    int idx = bid * 256 + threadIdx.x;
    int row = idx >> 8;
    int c4 = (idx & 255) << 2;
    int b = row / 3072, l = row - b * 3072;
    const float* src = (l < 2048)
        ? (x + ((size_t)b * 2048 + l) * 1024 + c4)
        : (ctx + ((size_t)b * 1024 + (l - 2048)) * 1024 + c4);
    float4 v = *(const float4*)src;
    bf16x4 o = { (bf16)v.x, (bf16)v.y, (bf16)v.z, (bf16)v.w };
    *(bf16x4*)(kvin + (size_t)row * 1024 + c4) = o;
    return;
  }
  const float* W; bf16* OT; int N, t;
  if (bid < 7168)      { W = Wq;  OT = WT;                        N = 1024; t = bid - 6144; }
  else if (bid < 9216) { W = Wkv; OT = WT + (size_t)1024 * 1024;  N = 2048; t = bid - 7168; }
  else                 { W = Wo;  OT = WoT;                       N = 1024; t = bid - 9216; }
  int nb = N >> 5;
  int n0 = (t % nb) * 32, k0 = (t / nb) * 32;
  int tx = threadIdx.x & 31, ty = threadIdx.x >> 5;
  for (int i = 0; i < 4; i++) {
    int kk = ty + i * 8;
    tile[kk][tx] = W[(size_t)(k0 + kk) * N + n0 + tx];
  }
  __syncthreads();
  for (int i = 0; i < 4; i++) {
    int nn = ty + i * 8;
    OT[(size_t)(n0 + nn) * 1024 + k0 + tx] = (bf16)tile[tx][nn];
  }
}

// ---- fused QKV GEMM (R14, verified win — frozen): 256x128 tiles, BK=64,
// 512 thr (8 waves of 64x64), 16 K-steps. Swizzle: dest linear, source
// k-slot ^(row&7), read slot ((kh*4|quad)^(row&7)). 1-phase sync.
__global__ __launch_bounds__(512, 4) void gemm_qkv(
    const bf16* __restrict__ A, const bf16* __restrict__ Bt,
    const float* __restrict__ bq, const float* __restrict__ bkv,
    bf16* __restrict__ Qb, bf16* __restrict__ Kb, bf16* __restrict__ Vt) {
  int id = blockIdx.x;
  int col0, row0;
  if (id < 384) {
    col0 = 1024 + ((id & 15) << 7);
    row0 = (id >> 4) << 8;
  } else {
    int q = id - 384;
    col0 = (q & 7) << 7;
    int rb = q >> 3;
    row0 = (rb < 8 ? rb : rb + 4) << 8;
  }
  __shared__ bf16 As[256 * 64];
  __shared__ bf16 Bs[128 * 64];
  int tid = threadIdx.x;
  int wave = tid >> 6, lane = tid & 63;
  int lane15 = lane & 15, quad = lane >> 4;
  int wm = (wave & 3) * 64, wn = (wave >> 2) * 64;
  int sr = tid >> 3;                       // staging row within 64-row pass
  int ssl = ((tid & 7) ^ (sr & 7)) * 8;    // pre-swizzled source k-slot
  floatx4 acc[4][4] = {};
  for (int k0 = 0; k0 < 1024; k0 += 64) {
    for (int p = 0; p < 4; p++)
      async_ld16(A + (size_t)(row0 + p * 64 + sr) * 1024 + k0 + ssl,
                 &As[p * 4096 + tid * 8]);
    for (int p = 0; p < 2; p++)
      async_ld16(Bt + (size_t)(col0 + p * 64 + sr) * 1024 + k0 + ssl,
                 &Bs[p * 4096 + tid * 8]);
    __syncthreads();
    for (int kh = 0; kh < 2; kh++) {
      bf16x8 af[4], bfr[4];
      for (int t = 0; t < 4; t++) {
        int row = wm + t * 16 + lane15;
        af[t] = *(const bf16x8*)(
            &As[row * 64 + (((kh << 2) | quad) ^ (row & 7)) * 8]);
      }
      for (int t = 0; t < 4; t++) {
        int row = wn + t * 16 + lane15;
        bfr[t] = *(const bf16x8*)(
            &Bs[row * 64 + (((kh << 2) | quad) ^ (row & 7)) * 8]);
      }
      for (int tm = 0; tm < 4; tm++)
        for (int tn = 0; tn < 4; tn++)
          acc[tm][tn] = mfma16(af[tm], bfr[tn], acc[tm][tn]);
    }
    __syncthreads();
  }
  float bv[4];
  for (int tn = 0; tn < 4; tn++) {
    int col = col0 + wn + tn * 16 + lane15;
    bv[tn] = (col < 1024) ? bq[col] : bkv[col - 1024];
  }
  int bb = row0 / 3072;
  int l0 = row0 - bb * 3072;
  if (col0 < 1024) {           // Q (self rows guaranteed by decode)
    const float SQ = 0.18033688011f;  // 0.125 * log2(e)
    for (int tm = 0; tm < 4; tm++)
      for (int r = 0; r < 4; r++) {
        size_t grow = (size_t)bb * 2048 + l0 + wm + tm * 16 + quad * 4 + r;
        for (int tn = 0; tn < 4; tn++)
          Qb[grow * 1024 + col0 + wn + tn * 16 + lane15] =
              (bf16)((acc[tm][tn][r] + bv[tn]) * SQ);
      }
  } else if (col0 < 2048) {    // K
    for (int tm = 0; tm < 4; tm++)
      for (int r = 0; r < 4; r++) {
        size_t grow = row0 + wm + tm * 16 + quad * 4 + r;
        for (int tn = 0; tn < 4; tn++)
          Kb[grow * 1024 + (col0 - 1024) + wn + tn * 16 + lane15] =
              (bf16)(acc[tm][tn][r] + bv[tn]);
      }
  } else {                     // V, transposed
    for (int tm = 0; tm < 4; tm++) {
      int lr = l0 + wm + tm * 16 + quad * 4;
      for (int tn = 0; tn < 4; tn++) {
        int c = col0 - 2048 + wn + tn * 16 + lane15;
        bf16x4 pk = { (bf16)(acc[tm][tn][0] + bv[tn]),
                      (bf16)(acc[tm][tn][1] + bv[tn]),
                      (bf16)(acc[tm][tn][2] + bv[tn]),
                      (bf16)(acc[tm][tn][3] + bv[tn]) };
        *(bf16x4*)(Vt + ((size_t)bb * 1024 + c) * 3072 + lr) = pk;
      }
    }
  }
}

// ---- O-proj GEMM (R21): third application of the verified fewer-fatter-
// K-steps lever. 128x64 tile, BK=128 (was 64): 8 K-steps, per wave/step
// 24 ds_read_b128 : 32 mfma. LDS 48 KB (< 64 KB/block at the grid-fixed
// 2 blocks/CU). Swizzle re-derived for 256B row stride: 16 k-slots,
// source ((tid&15)^(sr&7))*8, read (((kh<<2)|quad)^(row&7)) — LDS slot j
// holds global slot j^(row&7) on both sides (pass stride 16 == 0 mod 8);
// read phase = 2 lanes/bank-group (free). Registers unchanged.
__global__ __launch_bounds__(256) void gemm_o(
    const bf16* __restrict__ A, const bf16* __restrict__ Bt,
    const float* __restrict__ bias, float* __restrict__ O) {
  int col0 = blockIdx.x * 64, row0 = blockIdx.y * 128;
  __shared__ bf16 As[128 * 128];
  __shared__ bf16 Bs[64 * 128];
  int tid = threadIdx.x;
  int wave = tid >> 6, lane = tid & 63;
  int lane15 = lane & 15, quad = lane >> 4;
  int wm = (wave & 1) * 64, wn = (wave >> 1) * 32;
  int sr = tid >> 4;                        // 0..15: staging row within pass
  int ssl = ((tid & 15) ^ (sr & 7)) * 8;    // pre-swizzled source k-slot
  floatx4 acc[4][2] = {};
  for (int k0 = 0; k0 < 1024; k0 += 128) {
    for (int p = 0; p < 8; p++)
      async_ld16(A + (size_t)(row0 + p * 16 + sr) * 1024 + k0 + ssl,
                 &As[p * 2048 + tid * 8]);
    for (int p = 0; p < 4; p++)
      async_ld16(Bt + (size_t)(col0 + p * 16 + sr) * 1024 + k0 + ssl,
                 &Bs[p * 2048 + tid * 8]);
    __syncthreads();
    for (int kh = 0; kh < 4; kh++) {
      bf16x8 af[4], bfr[2];
      for (int t = 0; t < 4; t++) {
        int row = wm + t * 16 + lane15;
        af[t] = *(const bf16x8*)(
            &As[row * 128 + (((kh << 2) | quad) ^ (row & 7)) * 8]);
      }
      for (int t = 0; t < 2; t++) {
        int row = wn + t * 16 + lane15;
        bfr[t] = *(const bf16x8*)(
            &Bs[row * 128 + (((kh << 2) | quad) ^ (row & 7)) * 8]);
      }
      for (int tm = 0; tm < 4; tm++)
        for (int tn = 0; tn < 2; tn++)
          acc[tm][tn] = mfma16(af[tm], bfr[tn], acc[tm][tn]);
    }
    __syncthreads();
  }
  float bv[2];
  for (int tn = 0; tn < 2; tn++)
    bv[tn] = bias[col0 + wn + tn * 16 + lane15];
  for (int tm = 0; tm < 4; tm++)
    for (int r = 0; r < 4; r++) {
      size_t grow = row0 + wm + tm * 16 + quad * 4 + r;
      for (int tn = 0; tn < 2; tn++)
        O[grow * 1024 + col0 + wn + tn * 16 + lane15] = acc[tm][tn][r] + bv[tn];
    }
}

// ---- flash attention (R15 exact — the verified ~61 µs floor; frozen).
// Ledger: Lacc-MFMA (R7), reg-direct K/V (R9), lp[4] split (R16), qt
// remap (R18) all regressed. Zero register headroom; decode is load-
// bearing (longest-first + bh-low-bits).
__global__ __launch_bounds__(256, 4) void flash_attn(
    const bf16* __restrict__ Qb, const bf16* __restrict__ Kb,
    const bf16* __restrict__ Vt, bf16* __restrict__ Ob) {
  const int LD = 72;
  __shared__ bf16 Ks[2][64 * LD];   // [grp][key][dh]
  __shared__ bf16 Vs[2][64 * LD];   // [grp][dh][key]
  int tid = threadIdx.x;
  int wave = tid >> 6, lane = tid & 63;
  int qsub = wave & 1, grp = wave >> 1;
  int l31 = lane & 31, half = lane >> 5;
  int blk = blockIdx.x;
  int qt = 31 - (blk >> 5);      // longest first; bh in low bits -> same XCD
  int bh = blk & 31;
  int h = bh & 15, b = bh >> 4;
  int q0 = qt * 64;
  int qw0 = q0 + qsub * 32;
  int qq = qw0 + l31;            // this lane's q (col of S^T)

  const bf16* qrow = Qb + ((size_t)(b * 2048 + qq)) * 1024 + h * 64 + half * 8;
  bf16x8 qf[4];
  for (int c = 0; c < 4; c++) qf[c] = *(const bf16x8*)(qrow + c * 16);

  floatx16 Oacc[2] = {};
  float l_part = 0.f;

  int nself = qt + 1;            // 64-key self tiles
  int T = nself + 16;
  int iters = (T + 1 - grp) >> 1;
  int max_iters = (T + 1) >> 1;
  const bf16* kbase = Kb + (size_t)(b * 3072) * 1024 + h * 64;
  const bf16* vbase = Vt + ((size_t)b * 1024 + h * 64) * 3072;

  int tidg = qsub * 64 + lane;
  int sr = tidg >> 1, sc = (tidg & 1) * 32;
  bf16x8 kreg[4], vreg[4];
  auto prefetch = [&](int t) {
    int keyrow = (t < nself) ? t * 64 : 2048 + (t - nself) * 64;
    const bf16* kp = kbase + (size_t)(keyrow + sr) * 1024 + sc;
    const bf16* vp = vbase + (size_t)sr * 3072 + keyrow + sc;
    for (int j = 0; j < 4; j++) {
      kreg[j] = *(const bf16x8*)(kp + j * 8);
      vreg[j] = *(const bf16x8*)(vp + j * 8);
    }
  };
  int t = grp;
  prefetch(t);

  bf16* ksg = &Ks[grp][0];
  bf16* vsg = &Vs[grp][0];
  for (int it = 0; it < max_iters; it++) {
    bool act = it < iters;
    int keyrow = 0;
    if (act) keyrow = (t < nself) ? t * 64 : 2048 + (t - nself) * 64;
    __syncthreads();
    if (act)
      for (int j = 0; j < 4; j++) {
        *(bf16x8*)(&ksg[sr * LD + sc + j * 8]) = kreg[j];
        *(bf16x8*)(&vsg[sr * LD + sc + j * 8]) = vreg[j];
      }
    __syncthreads();
    if (act && t + 2 < T) prefetch(t + 2);
    if (act) {
      bool is_self = t < nself;
      uintx4 pf[4];
      for (int kt = 0; kt < 2; kt++) {
        floatx16 st = {};
        const bf16* ka = &ksg[(kt * 32 + l31) * LD + half * 8];
        __builtin_amdgcn_s_setprio(1);
        for (int c = 0; c < 4; c++)
          st = mfma32(*(const bf16x8*)(ka + c * 16), qf[c], st);
        __builtin_amdgcn_s_setprio(0);
        bool need_mask = is_self && (keyrow + kt * 32 + 31 > qw0);
        float p[16];
        for (int r = 0; r < 16; r++) {
          float e = __builtin_amdgcn_exp2f(st[r]);
          if (need_mask) {
            int key = keyrow + kt * 32 + (r & 3) + 8 * (r >> 2) + half * 4;
            if (key > qq) e = 0.f;
          }
          p[r] = e;
          l_part += e;
        }
        unsigned pk[8];
        for (int m2 = 0; m2 < 8; m2++) {
          bf16x2 two = { (bf16)p[2 * m2], (bf16)p[2 * m2 + 1] };
          pk[m2] = __builtin_bit_cast(unsigned, two);
        }
        for (int c2 = 0; c2 < 2; c2++) {
          // swap(a,b): out0 = {a.lo_lanes, b.lo_lanes}, out1 = {a.hi, b.hi}
          auto s02 = __builtin_amdgcn_permlane32_swap(
              pk[4 * c2 + 0], pk[4 * c2 + 2], false, false);
          auto s13 = __builtin_amdgcn_permlane32_swap(
              pk[4 * c2 + 1], pk[4 * c2 + 3], false, false);
          int c = kt * 2 + c2;
          pf[c][0] = s02[0];
          pf[c][1] = s13[0];
          pf[c][2] = s02[1];
          pf[c][3] = s13[1];
        }
      }
      __builtin_amdgcn_s_setprio(1);
      for (int vt = 0; vt < 2; vt++) {
        const bf16* va = &vsg[(vt * 32 + l31) * LD + half * 8];
        for (int c = 0; c < 4; c++)
          Oacc[vt] = mfma32(__builtin_bit_cast(bf16x8, pf[c]),
                            *(const bf16x8*)(va + c * 16), Oacc[vt]);
      }
      __builtin_amdgcn_s_setprio(0);
    }
    t += 2;
  }
  float l_tot = l_part + __shfl_xor(l_part, 32, 64);
  __syncthreads();
  float* Mb = (float*)&Ks[0][0];
  float* Lg = Mb + 4096;
  if (grp == 1) {
    for (int vt = 0; vt < 2; vt++)
      for (int r = 0; r < 16; r++)
        Mb[((qsub * 2 + vt) * 16 + r) * 64 + lane] = Oacc[vt][r];
    if (half == 0) Lg[(2 + qsub) * 32 + l31] = l_tot;
  } else if (half == 0) {
    Lg[qsub * 32 + l31] = l_tot;
  }
  __syncthreads();
  if (grp == 0) {
    for (int r = 0; r < 16; r++) {
      int qr = (r & 3) + 8 * (r >> 2) + half * 4;
      float inv = 1.0f / (Lg[qsub * 32 + qr] + Lg[(2 + qsub) * 32 + qr]);
      for (int vt = 0; vt < 2; vt++) {
        float o = Oacc[vt][r] + Mb[((qsub * 2 + vt) * 16 + r) * 64 + lane];
        Ob[(size_t)(b * 2048 + qw0 + qr) * 1024 + h * 64 + vt * 32 + l31] =
            (bf16)(o * inv);
      }
    }
  }
}

extern "C" void kernel_launch(void* const* d_in, const int* in_sizes, int n_in,
                              void* d_out, int out_size, void* d_ws,
                              size_t ws_size, hipStream_t stream) {
  const float* x   = (const float*)d_in[0];
  const float* ctx = (const float*)d_in[1];
  const float* Wq  = (const float*)d_in[2];
  const float* bq  = (const float*)d_in[3];
  const float* Wkv = (const float*)d_in[4];
  const float* bkv = (const float*)d_in[5];
  const float* Wo  = (const float*)d_in[6];
  const float* bo  = (const float*)d_in[7];
  float* out = (float*)d_out;

  bf16* p = (bf16*)d_ws;
  bf16* kvin = p;   p += (size_t)6144 * 1024;      // x||context bf16
  bf16* WT   = p;   p += (size_t)3072 * 1024;      // WqT | WkvT
  bf16* WoT  = p;   p += (size_t)1024 * 1024;
  bf16* Qb   = p;   p += (size_t)4096 * 1024;
  bf16* Kb   = p;   p += (size_t)6144 * 1024;
  bf16* Vt   = p;   p += (size_t)2 * 1024 * 3072;  // V transposed [b][dh][l]
  bf16* Ob   = p;

  prep<<<10240, 256, 0, stream>>>(x, ctx, Wq, Wkv, Wo, kvin, WT, WoT);
  gemm_qkv<<<512, 512, 0, stream>>>(kvin, WT, bq, bkv, Qb, Kb, Vt);
  flash_attn<<<1024, 256, 0, stream>>>(Qb, Kb, Vt, Ob);
  gemm_o<<<dim3(16, 32), 256, 0, stream>>>(Ob, WoT, bo, out);
}